// Round 12
// baseline (256.067 us; speedup 1.0000x reference)
//
#include <hip/hip_runtime.h>
#include <math.h>

#define NATOMS  512
#define MROWS   64
#define BATCH   65536
#define BT      4           // batch columns per block (1 per wave)
#define NSPARSE 5
#define DEPSF   1e-6f

typedef float v2f __attribute__((ext_vector_type(2)));

// ---------------------------------------------------------------------------
// prep: gram = D^T D (f64 accumulate -> f32) + diag extract.
// ---------------------------------------------------------------------------
__global__ void ksvd_prep(const float* __restrict__ D,
                          float* __restrict__ gram,
                          float* __restrict__ diag) {
  const int idx = blockIdx.x * 256 + threadIdx.x;     // 0 .. 512*512-1
  const int i = idx >> 9;
  const int j = idx & (NATOMS - 1);
  double acc = 0.0;
#pragma unroll 8
  for (int m = 0; m < MROWS; ++m)
    acc += (double)D[m * NATOMS + i] * (double)D[m * NATOMS + j];
  const float g = (float)acc;
  gram[idx] = g;
  if (i == j) diag[i] = g;
}

// ---------------------------------------------------------------------------
// wave64 max-reduce on the VALU via DPP (no LDS ops, no lgkmcnt waits).
// ---------------------------------------------------------------------------
__device__ __forceinline__ float wave_max_nonneg(float x) {
  int v = __builtin_bit_cast(int, x);
#define DPP_MAX_STEP(ctrl)                                                   \
  {                                                                          \
    const int t = __builtin_amdgcn_update_dpp(0, v, (ctrl), 0xf, 0xf, true); \
    v = __builtin_bit_cast(                                                  \
        int, fmaxf(__builtin_bit_cast(float, v), __builtin_bit_cast(float, t))); \
  }
  DPP_MAX_STEP(0x111)   // row_shr:1
  DPP_MAX_STEP(0x112)   // row_shr:2
  DPP_MAX_STEP(0x114)   // row_shr:4
  DPP_MAX_STEP(0x118)   // row_shr:8
  DPP_MAX_STEP(0x142)   // row_bcast15
  DPP_MAX_STEP(0x143)   // row_bcast31
#undef DPP_MAX_STEP
  return __builtin_bit_cast(float, __builtin_amdgcn_readlane(v, 63));
}

// by-VALUE float readlane (no address-taking anywhere)
__device__ __forceinline__ float readlane_f(float v, int l) {
  return __builtin_bit_cast(float,
      __builtin_amdgcn_readlane(__builtin_bit_cast(int, v), l));
}

// select one of 8 VALUES by wave-uniform slot sl: pure cndmask chain.
// (macro over explicit values -- arrays are only ever constant-indexed,
//  so SROA keeps them in registers; R11's pointer-based helper triggered
//  promote-alloca-to-LDS and a 1.45x regression)
#define SEL8V(r, sl, x0, x1, x2, x3, x4, x5, x6, x7)                         \
  {                                                                          \
    r = (x0);                                                                \
    r = ((sl) == 1) ? (x1) : r; r = ((sl) == 2) ? (x2) : r;                  \
    r = ((sl) == 3) ? (x3) : r; r = ((sl) == 4) ? (x4) : r;                  \
    r = ((sl) == 5) ? (x5) : r; r = ((sl) == 6) ? (x6) : r;                  \
    r = ((sl) == 7) ? (x7) : r;                                              \
  }

// ---------------------------------------------------------------------------
// main: block = 4 waves = 4 batch columns (one per wave). R9 base +
// critical-path de-memorization: per-round rhs/arow/gdiag come from
// registers via cndmask-chain + readlane (gram is exactly symmetric so
// gram[idx][idxs[j]] == gc[j]@idx; diag pre-loaded to registers at phase-2
// entry). The only k-loop memory op left is the next-round gc vector load
// (a full round of latency slack). All extracted values are bit-identical
// to the loads they replace -> absmax must stay exactly 0.015625.
// ---------------------------------------------------------------------------
__global__ __launch_bounds__(256, 4) void ksvd_main(
    const float* __restrict__ X, const float* __restrict__ D,
    const float* __restrict__ gram, const float* __restrict__ diag,
    float* __restrict__ out) {
  __shared__ union {
    float4 xs4[MROWS][BT / 2];       // 2 KB: {x2p,x2p,x2p+1,x2p+1} per m
    float  dtxT[BT][NATOMS];         // 8 KB: dtx transposed per column
  } sh;                              // -> 8192 B total

  const int t    = threadIdx.x;
  const int lane = t & 63;
  const int wave = t >> 6;                      // 0..3
  const int b0   = blockIdx.x * BT;

  // ---- stage X tile (64 m x 4 c) duplicated: xs4[m][p]={x2p,x2p,x2p+1,x2p+1}
  if (t < MROWS * 2) {
    const int m = t >> 1, p = t & 1;
    const float x0 = X[(size_t)m * BATCH + b0 + 2 * p];
    const float x1 = X[(size_t)m * BATCH + b0 + 2 * p + 1];
    float4 v; v.x = x0; v.y = x0; v.z = x1; v.w = x1;
    sh.xs4[m][p] = v;
  }
  __syncthreads();

  // ---- phase 1: lane owns atom pair (a0, a0+1), a0 = 128*wave + 2*lane
  const int a0 = wave * 128 + 2 * lane;
  v2f accA[BT], accB[BT];
#pragma unroll
  for (int c = 0; c < BT; ++c) {
    accA[c].x = 0.f; accA[c].y = 0.f;
    accB[c].x = 0.f; accB[c].y = 0.f;
  }

#pragma unroll 4
  for (int m = 0; m < MROWS; m += 2) {
    const v2f dA = *reinterpret_cast<const v2f*>(&D[m * NATOMS + a0]);
    const v2f dB = *reinterpret_cast<const v2f*>(&D[(m + 1) * NATOMS + a0]);
    const float4 xa0 = sh.xs4[m][0];
    const float4 xa1 = sh.xs4[m][1];
    const float4 xb0 = sh.xs4[m + 1][0];
    const float4 xb1 = sh.xs4[m + 1][1];
    v2f xv;
    xv.x = xa0.x; xv.y = xa0.y; accA[0] = __builtin_elementwise_fma(dA, xv, accA[0]);
    xv.x = xa0.z; xv.y = xa0.w; accA[1] = __builtin_elementwise_fma(dA, xv, accA[1]);
    xv.x = xa1.x; xv.y = xa1.y; accA[2] = __builtin_elementwise_fma(dA, xv, accA[2]);
    xv.x = xa1.z; xv.y = xa1.w; accA[3] = __builtin_elementwise_fma(dA, xv, accA[3]);
    xv.x = xb0.x; xv.y = xb0.y; accB[0] = __builtin_elementwise_fma(dB, xv, accB[0]);
    xv.x = xb0.z; xv.y = xb0.w; accB[1] = __builtin_elementwise_fma(dB, xv, accB[1]);
    xv.x = xb1.x; xv.y = xb1.y; accB[2] = __builtin_elementwise_fma(dB, xv, accB[2]);
    xv.x = xb1.z; xv.y = xb1.w; accB[3] = __builtin_elementwise_fma(dB, xv, accB[3]);
  }
  __syncthreads();   // all xs4 reads complete before dtxT overwrites the union

#pragma unroll
  for (int c = 0; c < BT; ++c) {
    const v2f s = accA[c] + accB[c];
    *reinterpret_cast<v2f*>(&sh.dtxT[c][a0]) = s;
  }
  __syncthreads();

  // ---- phase 2: this wave's column; lane owns 8 consecutive atoms 8l..8l+7
  const int cglob = b0 + wave;
  float dtxr[8], diagr[8];
  {
    const float4 f0 = *reinterpret_cast<const float4*>(&sh.dtxT[wave][8 * lane]);
    const float4 f1 = *reinterpret_cast<const float4*>(&sh.dtxT[wave][8 * lane + 4]);
    dtxr[0] = f0.x; dtxr[1] = f0.y; dtxr[2] = f0.z; dtxr[3] = f0.w;
    dtxr[4] = f1.x; dtxr[5] = f1.y; dtxr[6] = f1.z; dtxr[7] = f1.w;
    // diag -> registers (2 coalesced float4 from global; 2 KB, L2-resident;
    // off the critical path -- first use is ~200 cy later at k=0 Cholesky)
    const float4 g0 = *reinterpret_cast<const float4*>(&diag[8 * lane]);
    const float4 g1 = *reinterpret_cast<const float4*>(&diag[8 * lane + 4]);
    diagr[0] = g0.x; diagr[1] = g0.y; diagr[2] = g0.z; diagr[3] = g0.w;
    diagr[4] = g1.x; diagr[5] = g1.y; diagr[6] = g1.z; diagr[7] = g1.w;
  }

  int   idxs[NSPARSE];
  float gc[NSPARSE - 1][8];                 // cached gram columns (f32)
  float L[NSPARSE][NSPARSE];                // lower-tri Cholesky (static idx)
  float inv_d[NSPARSE];
  float y[NSPARSE];
  float sol[NSPARSE];

#pragma unroll
  for (int k = 0; k < NSPARSE; ++k) {
    // corr = dtx - sum_s sol[s]*gc_s (f32); f32-key argmax, first-max ties
    float bv   = -1.0f;
    int   bn   = 0;
    float bdtx = 0.0f;                       // dtx value of the local winner
#pragma unroll
    for (int jj = 0; jj < 8; ++jj) {
      float cv = dtxr[jj];
#pragma unroll
      for (int s = 0; s < k; ++s) cv -= sol[s] * gc[s][jj];
      const float av = fabsf(cv);
      if (av > bv) { bv = av; bn = 8 * lane + jj; bdtx = dtxr[jj]; }
    }
    // wave max on the VALU (DPP), then owner = lowest lane holding the max
    const float wmax = wave_max_nonneg(bv);
    const unsigned long long own = __ballot(bv == wmax);
    const int owner = __ffsll((long long)own) - 1;    // lowest lane: first-max
    int idx = __builtin_amdgcn_readlane(bn, owner);
    idx = __builtin_amdgcn_readfirstlane(idx);        // uniform (SGPR)
    idxs[k] = idx;
    const int sl = idx & 7;                   // slot within owner lane
    const int ol = idx >> 3;                  // owner lane of atom idx

    // rhs[k] = dtx[idx]: winner's own dtx value (exact, zero memory)
    const float rhsk = readlane_f(bdtx, owner);

    // gram column for future corr updates (vector, L2-resident; consumed
    // next round -> a full round of latency slack)
    if (k < NSPARSE - 1) {
      const float4 g0 = *reinterpret_cast<const float4*>(
          &gram[(size_t)idx * NATOMS + 8 * lane]);
      const float4 g1 = *reinterpret_cast<const float4*>(
          &gram[(size_t)idx * NATOMS + 8 * lane + 4]);
      gc[k][0] = g0.x; gc[k][1] = g0.y; gc[k][2] = g0.z; gc[k][3] = g0.w;
      gc[k][4] = g1.x; gc[k][5] = g1.y; gc[k][6] = g1.z; gc[k][7] = g1.w;
    }

    // Gram row k: arow[j] = gram[idx][idxs[j]] == gc[j]@atom-idx (symmetry,
    // exact); gdiag from the diag registers. Pure cndmask+readlane.
    float arowf[NSPARSE];
#pragma unroll
    for (int j = 0; j < k; ++j) {
      float v;
      SEL8V(v, sl, gc[j][0], gc[j][1], gc[j][2], gc[j][3],
                   gc[j][4], gc[j][5], gc[j][6], gc[j][7]);
      arowf[j] = readlane_f(v, ol);
    }
    float gdv;
    SEL8V(gdv, sl, diagr[0], diagr[1], diagr[2], diagr[3],
                   diagr[4], diagr[5], diagr[6], diagr[7]);
    const float gdiag = readlane_f(gdv, ol);

    // incremental Cholesky row k of (G_active + eps*I), rsqrtf-based
    float ss = gdiag + DEPSF;
#pragma unroll
    for (int j = 0; j < k; ++j) {
      float w = arowf[j];
#pragma unroll
      for (int tt = 0; tt < j; ++tt) w -= L[k][tt] * L[j][tt];
      w *= inv_d[j];
      L[k][j] = w;
      ss -= w * w;
    }
    const float inv = rsqrtf(ss);
    L[k][k]  = ss * inv;                    // = sqrt(ss)
    inv_d[k] = inv;

    // forward substitution: only y[k] is new (y[0..k-1] unchanged)
    {
      float s2 = rhsk;
#pragma unroll
      for (int j = 0; j < k; ++j) s2 -= L[k][j] * y[j];
      y[k] = s2 * inv;
    }
    // backward substitution (full, sol changes every round)
#pragma unroll
    for (int i = k; i >= 0; --i) {
      float s2 = y[i];
#pragma unroll
      for (int j = i + 1; j <= k; ++j) s2 -= L[j][i] * sol[j];
      sol[i] = s2 * inv_d[i];
    }
  }

  // ---- epilogue: scatter the 5 coefficients (out pre-zeroed by memset)
  if (lane == 0) {
#pragma unroll
    for (int s = 0; s < NSPARSE; ++s)
      out[(size_t)idxs[s] * BATCH + cglob] = sol[s];
  }
}

// ---------------------------------------------------------------------------
extern "C" void kernel_launch(void* const* d_in, const int* in_sizes, int n_in,
                              void* d_out, int out_size, void* d_ws,
                              size_t ws_size, hipStream_t stream) {
  (void)in_sizes; (void)n_in; (void)out_size; (void)ws_size;
  const float* X = (const float*)d_in[0];   // (64, 65536)
  const float* D = (const float*)d_in[1];   // (64, 512)
  float* out = (float*)d_out;               // (512, 65536)
  float* gram = (float*)d_ws;                           // 1 MB
  float* diag = (float*)((char*)d_ws + (1 << 20));      // 2 KB

  ksvd_prep<<<(NATOMS * NATOMS) / 256, 256, 0, stream>>>(D, gram, diag);
  hipMemsetAsync(out, 0, (size_t)NATOMS * BATCH * sizeof(float), stream);
  ksvd_main<<<BATCH / BT, 256, 0, stream>>>(X, D, gram, diag, out);
}

// Round 13
// 246.048 us; speedup vs baseline: 1.0407x; 1.0407x over previous
//
#include <hip/hip_runtime.h>
#include <math.h>

#define NATOMS  512
#define MROWS   64
#define BATCH   65536
#define BT      4           // batch columns per block (1 per wave)
#define NSPARSE 5
#define DEPSF   1e-6f

typedef float v2f __attribute__((ext_vector_type(2)));

// ---------------------------------------------------------------------------
// prep: gram = D^T D (f64 accumulate -> f32). 1024 blocks x 256 threads.
// ---------------------------------------------------------------------------
__global__ void ksvd_prep(const float* __restrict__ D,
                          float* __restrict__ gram) {
  const int idx = blockIdx.x * 256 + threadIdx.x;     // 0 .. 512*512-1
  const int i = idx >> 9;
  const int j = idx & (NATOMS - 1);
  double acc = 0.0;
#pragma unroll 8
  for (int m = 0; m < MROWS; ++m)
    acc += (double)D[m * NATOMS + i] * (double)D[m * NATOMS + j];
  gram[idx] = (float)acc;
}

// ---------------------------------------------------------------------------
// wave64 max-reduce on the VALU via DPP (no LDS ops, no lgkmcnt waits).
// ---------------------------------------------------------------------------
__device__ __forceinline__ float wave_max_nonneg(float x) {
  int v = __builtin_bit_cast(int, x);
#define DPP_MAX_STEP(ctrl)                                                   \
  {                                                                          \
    const int t = __builtin_amdgcn_update_dpp(0, v, (ctrl), 0xf, 0xf, true); \
    v = __builtin_bit_cast(                                                  \
        int, fmaxf(__builtin_bit_cast(float, v), __builtin_bit_cast(float, t))); \
  }
  DPP_MAX_STEP(0x111)   // row_shr:1
  DPP_MAX_STEP(0x112)   // row_shr:2
  DPP_MAX_STEP(0x114)   // row_shr:4
  DPP_MAX_STEP(0x118)   // row_shr:8
  DPP_MAX_STEP(0x142)   // row_bcast15
  DPP_MAX_STEP(0x143)   // row_bcast31
#undef DPP_MAX_STEP
  return __builtin_bit_cast(float, __builtin_amdgcn_readlane(v, 63));
}

// by-VALUE float readlane (no address-taking anywhere)
__device__ __forceinline__ float readlane_f(float v, int l) {
  return __builtin_bit_cast(float,
      __builtin_amdgcn_readlane(__builtin_bit_cast(int, v), l));
}

// ---------------------------------------------------------------------------
// main: block = 4 waves = 4 batch columns (one per wave). R9 structure
// (union LDS 8 KB, launch_bounds(256,4), pk-fma phase 1) + two register-
// sourced critical-path values:
//  - rhs[k] = dtx[idx] extracted from the argmax winner's own register
//    (readlane on the existing owner resolve) -> no per-round LDS read.
//  - arow[j] = gram[idx][idxs[j]] == gc[j]@atom-idx (gram exactly
//    symmetric) -> 7 uniform-cond cndmask + 1 readlane (SGPR lane), using
//    ONLY the existing gc array with literal indices -> no per-round
//    scalar gram loads. gdiag stays a single uniform load (hides under
//    the extraction arithmetic). No new arrays (R11/R12 lesson: any new
//    8-float array tipped regalloc into spilling gc to scratch).
// All substituted values are bit-identical -> absmax must stay 0.015625.
// ---------------------------------------------------------------------------
__global__ __launch_bounds__(256, 4) void ksvd_main(
    const float* __restrict__ X, const float* __restrict__ D,
    const float* __restrict__ gram, float* __restrict__ out) {
  __shared__ union {
    float4 xs4[MROWS][BT / 2];       // 2 KB: {x2p,x2p,x2p+1,x2p+1} per m
    float  dtxT[BT][NATOMS];         // 8 KB: dtx transposed per column
  } sh;                              // -> 8192 B total

  const int t    = threadIdx.x;
  const int lane = t & 63;
  const int wave = t >> 6;                      // 0..3
  const int b0   = blockIdx.x * BT;

  // ---- stage X tile (64 m x 4 c) duplicated: xs4[m][p]={x2p,x2p,x2p+1,x2p+1}
  if (t < MROWS * 2) {
    const int m = t >> 1, p = t & 1;
    const float x0 = X[(size_t)m * BATCH + b0 + 2 * p];
    const float x1 = X[(size_t)m * BATCH + b0 + 2 * p + 1];
    float4 v; v.x = x0; v.y = x0; v.z = x1; v.w = x1;
    sh.xs4[m][p] = v;
  }
  __syncthreads();

  // ---- phase 1: lane owns atom pair (a0, a0+1), a0 = 128*wave + 2*lane
  const int a0 = wave * 128 + 2 * lane;
  v2f accA[BT], accB[BT];
#pragma unroll
  for (int c = 0; c < BT; ++c) {
    accA[c].x = 0.f; accA[c].y = 0.f;
    accB[c].x = 0.f; accB[c].y = 0.f;
  }

#pragma unroll 4
  for (int m = 0; m < MROWS; m += 2) {
    const v2f dA = *reinterpret_cast<const v2f*>(&D[m * NATOMS + a0]);
    const v2f dB = *reinterpret_cast<const v2f*>(&D[(m + 1) * NATOMS + a0]);
    const float4 xa0 = sh.xs4[m][0];
    const float4 xa1 = sh.xs4[m][1];
    const float4 xb0 = sh.xs4[m + 1][0];
    const float4 xb1 = sh.xs4[m + 1][1];
    v2f xv;
    xv.x = xa0.x; xv.y = xa0.y; accA[0] = __builtin_elementwise_fma(dA, xv, accA[0]);
    xv.x = xa0.z; xv.y = xa0.w; accA[1] = __builtin_elementwise_fma(dA, xv, accA[1]);
    xv.x = xa1.x; xv.y = xa1.y; accA[2] = __builtin_elementwise_fma(dA, xv, accA[2]);
    xv.x = xa1.z; xv.y = xa1.w; accA[3] = __builtin_elementwise_fma(dA, xv, accA[3]);
    xv.x = xb0.x; xv.y = xb0.y; accB[0] = __builtin_elementwise_fma(dB, xv, accB[0]);
    xv.x = xb0.z; xv.y = xb0.w; accB[1] = __builtin_elementwise_fma(dB, xv, accB[1]);
    xv.x = xb1.x; xv.y = xb1.y; accB[2] = __builtin_elementwise_fma(dB, xv, accB[2]);
    xv.x = xb1.z; xv.y = xb1.w; accB[3] = __builtin_elementwise_fma(dB, xv, accB[3]);
  }
  __syncthreads();   // all xs4 reads complete before dtxT overwrites the union

#pragma unroll
  for (int c = 0; c < BT; ++c) {
    const v2f s = accA[c] + accB[c];
    *reinterpret_cast<v2f*>(&sh.dtxT[c][a0]) = s;
  }
  __syncthreads();

  // ---- phase 2: this wave's column; lane owns 8 consecutive atoms 8l..8l+7
  const int cglob = b0 + wave;
  float dtxr[8];
  {
    const float4 f0 = *reinterpret_cast<const float4*>(&sh.dtxT[wave][8 * lane]);
    const float4 f1 = *reinterpret_cast<const float4*>(&sh.dtxT[wave][8 * lane + 4]);
    dtxr[0] = f0.x; dtxr[1] = f0.y; dtxr[2] = f0.z; dtxr[3] = f0.w;
    dtxr[4] = f1.x; dtxr[5] = f1.y; dtxr[6] = f1.z; dtxr[7] = f1.w;
  }

  int   idxs[NSPARSE];
  float gc[NSPARSE - 1][8];                 // cached gram columns (f32)
  float L[NSPARSE][NSPARSE];                // lower-tri Cholesky (static idx)
  float inv_d[NSPARSE];
  float y[NSPARSE];
  float sol[NSPARSE];

#pragma unroll
  for (int k = 0; k < NSPARSE; ++k) {
    // corr = dtx - sum_s sol[s]*gc_s (f32); f32-key argmax, first-max ties
    float bv   = -1.0f;
    int   bn   = 0;
    float bdtx = 0.0f;                       // dtx value of the local winner
#pragma unroll
    for (int jj = 0; jj < 8; ++jj) {
      float cv = dtxr[jj];
#pragma unroll
      for (int s = 0; s < k; ++s) cv -= sol[s] * gc[s][jj];
      const float av = fabsf(cv);
      if (av > bv) { bv = av; bn = 8 * lane + jj; bdtx = dtxr[jj]; }
    }
    // wave max on the VALU (DPP), then owner = lowest lane holding the max
    const float wmax = wave_max_nonneg(bv);
    const unsigned long long own = __ballot(bv == wmax);
    const int owner = __ffsll((long long)own) - 1;    // lowest lane: first-max
    int idx = __builtin_amdgcn_readlane(bn, owner);
    idx = __builtin_amdgcn_readfirstlane(idx);        // pin uniform (SGPR)
    idxs[k] = idx;
    const int sl = idx & 7;                   // slot within owner lane (SGPR)
    const int ol = idx >> 3;                  // owner lane of atom idx (SGPR)

    // rhs[k] = dtx[idx]: the winner's own dtx value (exact, zero memory)
    const float rhsk = readlane_f(bdtx, owner);

    // gram column for future corr updates (vector, L2-resident; consumed
    // next round -> a full round of latency slack)
    if (k < NSPARSE - 1) {
      const float4 g0 = *reinterpret_cast<const float4*>(
          &gram[(size_t)idx * NATOMS + 8 * lane]);
      const float4 g1 = *reinterpret_cast<const float4*>(
          &gram[(size_t)idx * NATOMS + 8 * lane + 4]);
      gc[k][0] = g0.x; gc[k][1] = g0.y; gc[k][2] = g0.z; gc[k][3] = g0.w;
      gc[k][4] = g1.x; gc[k][5] = g1.y; gc[k][6] = g1.z; gc[k][7] = g1.w;
    }

    // gdiag: single uniform load (latency hides under arow extraction)
    const float gdiag = gram[(size_t)idx * NATOMS + idx];

    // Gram row k: arow[j] = gram[idx][idxs[j]] == gc[j]@atom-idx (symmetry,
    // exact). Uniform-slot cndmask chain + single readlane (SGPR lane).
    float arowf[NSPARSE];
#pragma unroll
    for (int j = 0; j < k; ++j) {
      float v = gc[j][0];
      v = (sl == 1) ? gc[j][1] : v;
      v = (sl == 2) ? gc[j][2] : v;
      v = (sl == 3) ? gc[j][3] : v;
      v = (sl == 4) ? gc[j][4] : v;
      v = (sl == 5) ? gc[j][5] : v;
      v = (sl == 6) ? gc[j][6] : v;
      v = (sl == 7) ? gc[j][7] : v;
      arowf[j] = readlane_f(v, ol);
    }

    // incremental Cholesky row k of (G_active + eps*I), rsqrtf-based
    float ss = gdiag + DEPSF;
#pragma unroll
    for (int j = 0; j < k; ++j) {
      float w = arowf[j];
#pragma unroll
      for (int tt = 0; tt < j; ++tt) w -= L[k][tt] * L[j][tt];
      w *= inv_d[j];
      L[k][j] = w;
      ss -= w * w;
    }
    const float inv = rsqrtf(ss);
    L[k][k]  = ss * inv;                    // = sqrt(ss)
    inv_d[k] = inv;

    // forward substitution: only y[k] is new (y[0..k-1] unchanged)
    {
      float s2 = rhsk;
#pragma unroll
      for (int j = 0; j < k; ++j) s2 -= L[k][j] * y[j];
      y[k] = s2 * inv;
    }
    // backward substitution (full, sol changes every round)
#pragma unroll
    for (int i = k; i >= 0; --i) {
      float s2 = y[i];
#pragma unroll
      for (int j = i + 1; j <= k; ++j) s2 -= L[j][i] * sol[j];
      sol[i] = s2 * inv_d[i];
    }
  }

  // ---- epilogue: scatter the 5 coefficients (out pre-zeroed by memset)
  if (lane == 0) {
#pragma unroll
    for (int s = 0; s < NSPARSE; ++s)
      out[(size_t)idxs[s] * BATCH + cglob] = sol[s];
  }
}

// ---------------------------------------------------------------------------
extern "C" void kernel_launch(void* const* d_in, const int* in_sizes, int n_in,
                              void* d_out, int out_size, void* d_ws,
                              size_t ws_size, hipStream_t stream) {
  (void)in_sizes; (void)n_in; (void)out_size; (void)ws_size;
  const float* X = (const float*)d_in[0];   // (64, 65536)
  const float* D = (const float*)d_in[1];   // (64, 512)
  float* out = (float*)d_out;               // (512, 65536)
  float* gram = (float*)d_ws;               // 1 MB scratch

  ksvd_prep<<<(NATOMS * NATOMS) / 256, 256, 0, stream>>>(D, gram);
  hipMemsetAsync(out, 0, (size_t)NATOMS * BATCH * sizeof(float), stream);
  ksvd_main<<<BATCH / BT, 256, 0, stream>>>(X, D, gram, out);
}

// Round 14
// 190.916 us; speedup vs baseline: 1.3413x; 1.2888x over previous
//
#include <hip/hip_runtime.h>
#include <math.h>

#define NATOMS  512
#define MROWS   64
#define BATCH   65536
#define BT      4           // batch columns per block (1 per wave)
#define NSPARSE 5
#define DEPSF   1e-6f

typedef float v2f __attribute__((ext_vector_type(2)));

// ---------------------------------------------------------------------------
// prep: gram = D^T D (f64 accumulate -> f32). 1024 blocks x 256 threads.
// ---------------------------------------------------------------------------
__global__ void ksvd_prep(const float* __restrict__ D,
                          float* __restrict__ gram) {
  const int idx = blockIdx.x * 256 + threadIdx.x;     // 0 .. 512*512-1
  const int i = idx >> 9;
  const int j = idx & (NATOMS - 1);
  double acc = 0.0;
#pragma unroll 8
  for (int m = 0; m < MROWS; ++m)
    acc += (double)D[m * NATOMS + i] * (double)D[m * NATOMS + j];
  gram[idx] = (float)acc;
}

// ---------------------------------------------------------------------------
// wave64 max-reduce on the VALU via DPP (no LDS ops, no lgkmcnt waits).
// ---------------------------------------------------------------------------
__device__ __forceinline__ float wave_max_nonneg(float x) {
  int v = __builtin_bit_cast(int, x);
#define DPP_MAX_STEP(ctrl)                                                   \
  {                                                                          \
    const int t = __builtin_amdgcn_update_dpp(0, v, (ctrl), 0xf, 0xf, true); \
    v = __builtin_bit_cast(                                                  \
        int, fmaxf(__builtin_bit_cast(float, v), __builtin_bit_cast(float, t))); \
  }
  DPP_MAX_STEP(0x111)   // row_shr:1
  DPP_MAX_STEP(0x112)   // row_shr:2
  DPP_MAX_STEP(0x114)   // row_shr:4
  DPP_MAX_STEP(0x118)   // row_shr:8
  DPP_MAX_STEP(0x142)   // row_bcast15
  DPP_MAX_STEP(0x143)   // row_bcast31
#undef DPP_MAX_STEP
  return __builtin_bit_cast(float, __builtin_amdgcn_readlane(v, 63));
}

// by-VALUE float readlane (no address-taking anywhere)
__device__ __forceinline__ float readlane_f(float v, int l) {
  return __builtin_bit_cast(float,
      __builtin_amdgcn_readlane(__builtin_bit_cast(int, v), l));
}

// ---------------------------------------------------------------------------
// main: block = 4 waves = 4 batch columns (one per wave). EXACT R9 structure
// (union LDS 8 KB, launch_bounds(256,4), pk-fma phase 1, gc register cache,
// scalar arow/gdiag loads) with ONE delta: rhs[k] = dtx[idx] is extracted
// from the argmax winner's own register (bdtx + readlane on the existing
// owner resolve) instead of a per-round uniform LDS read. The rhsf[] array
// becomes a scalar (round k only ever used rhsf[k]). Bit-identical values
// -> absmax must stay exactly 0.015625.
// R11-R13 lesson (3x confirmed): any extraction needing all 8 elements of a
// cached column simultaneously live spills gc to scratch (534 MB writes).
// This change adds ONE tracked scalar; no new arrays.
// ---------------------------------------------------------------------------
__global__ __launch_bounds__(256, 4) void ksvd_main(
    const float* __restrict__ X, const float* __restrict__ D,
    const float* __restrict__ gram, float* __restrict__ out) {
  __shared__ union {
    float4 xs4[MROWS][BT / 2];       // 2 KB: {x2p,x2p,x2p+1,x2p+1} per m
    float  dtxT[BT][NATOMS];         // 8 KB: dtx transposed per column
  } sh;                              // -> 8192 B total

  const int t    = threadIdx.x;
  const int lane = t & 63;
  const int wave = t >> 6;                      // 0..3
  const int b0   = blockIdx.x * BT;

  // ---- stage X tile (64 m x 4 c) duplicated: xs4[m][p]={x2p,x2p,x2p+1,x2p+1}
  if (t < MROWS * 2) {
    const int m = t >> 1, p = t & 1;
    const float x0 = X[(size_t)m * BATCH + b0 + 2 * p];
    const float x1 = X[(size_t)m * BATCH + b0 + 2 * p + 1];
    float4 v; v.x = x0; v.y = x0; v.z = x1; v.w = x1;
    sh.xs4[m][p] = v;
  }
  __syncthreads();

  // ---- phase 1: lane owns atom pair (a0, a0+1), a0 = 128*wave + 2*lane
  const int a0 = wave * 128 + 2 * lane;
  v2f accA[BT], accB[BT];
#pragma unroll
  for (int c = 0; c < BT; ++c) {
    accA[c].x = 0.f; accA[c].y = 0.f;
    accB[c].x = 0.f; accB[c].y = 0.f;
  }

#pragma unroll 4
  for (int m = 0; m < MROWS; m += 2) {
    const v2f dA = *reinterpret_cast<const v2f*>(&D[m * NATOMS + a0]);
    const v2f dB = *reinterpret_cast<const v2f*>(&D[(m + 1) * NATOMS + a0]);
    const float4 xa0 = sh.xs4[m][0];
    const float4 xa1 = sh.xs4[m][1];
    const float4 xb0 = sh.xs4[m + 1][0];
    const float4 xb1 = sh.xs4[m + 1][1];
    v2f xv;
    xv.x = xa0.x; xv.y = xa0.y; accA[0] = __builtin_elementwise_fma(dA, xv, accA[0]);
    xv.x = xa0.z; xv.y = xa0.w; accA[1] = __builtin_elementwise_fma(dA, xv, accA[1]);
    xv.x = xa1.x; xv.y = xa1.y; accA[2] = __builtin_elementwise_fma(dA, xv, accA[2]);
    xv.x = xa1.z; xv.y = xa1.w; accA[3] = __builtin_elementwise_fma(dA, xv, accA[3]);
    xv.x = xb0.x; xv.y = xb0.y; accB[0] = __builtin_elementwise_fma(dB, xv, accB[0]);
    xv.x = xb0.z; xv.y = xb0.w; accB[1] = __builtin_elementwise_fma(dB, xv, accB[1]);
    xv.x = xb1.x; xv.y = xb1.y; accB[2] = __builtin_elementwise_fma(dB, xv, accB[2]);
    xv.x = xb1.z; xv.y = xb1.w; accB[3] = __builtin_elementwise_fma(dB, xv, accB[3]);
  }
  __syncthreads();   // all xs4 reads complete before dtxT overwrites the union

#pragma unroll
  for (int c = 0; c < BT; ++c) {
    const v2f s = accA[c] + accB[c];
    *reinterpret_cast<v2f*>(&sh.dtxT[c][a0]) = s;
  }
  __syncthreads();

  // ---- phase 2: this wave's column; lane owns 8 consecutive atoms 8l..8l+7
  const int cglob = b0 + wave;
  float dtxr[8];
  {
    const float4 f0 = *reinterpret_cast<const float4*>(&sh.dtxT[wave][8 * lane]);
    const float4 f1 = *reinterpret_cast<const float4*>(&sh.dtxT[wave][8 * lane + 4]);
    dtxr[0] = f0.x; dtxr[1] = f0.y; dtxr[2] = f0.z; dtxr[3] = f0.w;
    dtxr[4] = f1.x; dtxr[5] = f1.y; dtxr[6] = f1.z; dtxr[7] = f1.w;
  }

  int   idxs[NSPARSE];
  float gc[NSPARSE - 1][8];                 // cached gram columns (f32)
  float L[NSPARSE][NSPARSE];                // lower-tri Cholesky (static idx)
  float inv_d[NSPARSE];
  float y[NSPARSE];
  float sol[NSPARSE];

#pragma unroll
  for (int k = 0; k < NSPARSE; ++k) {
    // corr = dtx - sum_s sol[s]*gc_s (f32); f32-key argmax, first-max ties
    float bv   = -1.0f;
    int   bn   = 0;
    float bdtx = 0.0f;                       // dtx value of the local winner
#pragma unroll
    for (int jj = 0; jj < 8; ++jj) {
      float cv = dtxr[jj];
#pragma unroll
      for (int s = 0; s < k; ++s) cv -= sol[s] * gc[s][jj];
      const float av = fabsf(cv);
      if (av > bv) { bv = av; bn = 8 * lane + jj; bdtx = dtxr[jj]; }
    }
    // wave max on the VALU (DPP), then owner = lowest lane holding the max
    const float wmax = wave_max_nonneg(bv);
    const unsigned long long own = __ballot(bv == wmax);
    const int owner = __ffsll((long long)own) - 1;    // lowest lane: first-max
    int idx = __builtin_amdgcn_readlane(bn, owner);
    idx = __builtin_amdgcn_readfirstlane(idx);        // pin uniform (SGPR)
    idxs[k] = idx;

    // rhs[k] = dtx[idx]: the winner's own dtx register (exact, zero memory)
    const float rhsk = readlane_f(bdtx, owner);

    // gram column for future corr updates (vector, L2-resident; consumed
    // next round -> a full round of latency slack)
    if (k < NSPARSE - 1) {
      const float4 g0 = *reinterpret_cast<const float4*>(
          &gram[(size_t)idx * NATOMS + 8 * lane]);
      const float4 g1 = *reinterpret_cast<const float4*>(
          &gram[(size_t)idx * NATOMS + 8 * lane + 4]);
      gc[k][0] = g0.x; gc[k][1] = g0.y; gc[k][2] = g0.z; gc[k][3] = g0.w;
      gc[k][4] = g1.x; gc[k][5] = g1.y; gc[k][6] = g1.z; gc[k][7] = g1.w;
    }

    // Gram row k entries: uniform (scalar) loads, as in R9
    float arowf[NSPARSE];
#pragma unroll
    for (int j = 0; j < k; ++j)
      arowf[j] = gram[(size_t)idx * NATOMS + idxs[j]];
    const float gdiag = gram[(size_t)idx * NATOMS + idx];

    // incremental Cholesky row k of (G_active + eps*I), rsqrtf-based
    float ss = gdiag + DEPSF;
#pragma unroll
    for (int j = 0; j < k; ++j) {
      float w = arowf[j];
#pragma unroll
      for (int tt = 0; tt < j; ++tt) w -= L[k][tt] * L[j][tt];
      w *= inv_d[j];
      L[k][j] = w;
      ss -= w * w;
    }
    const float inv = rsqrtf(ss);
    L[k][k]  = ss * inv;                    // = sqrt(ss)
    inv_d[k] = inv;

    // forward substitution: only y[k] is new (y[0..k-1] unchanged)
    {
      float s2 = rhsk;
#pragma unroll
      for (int j = 0; j < k; ++j) s2 -= L[k][j] * y[j];
      y[k] = s2 * inv;
    }
    // backward substitution (full, sol changes every round)
#pragma unroll
    for (int i = k; i >= 0; --i) {
      float s2 = y[i];
#pragma unroll
      for (int j = i + 1; j <= k; ++j) s2 -= L[j][i] * sol[j];
      sol[i] = s2 * inv_d[i];
    }
  }

  // ---- epilogue: scatter the 5 coefficients (out pre-zeroed by memset)
  if (lane == 0) {
#pragma unroll
    for (int s = 0; s < NSPARSE; ++s)
      out[(size_t)idxs[s] * BATCH + cglob] = sol[s];
  }
}

// ---------------------------------------------------------------------------
extern "C" void kernel_launch(void* const* d_in, const int* in_sizes, int n_in,
                              void* d_out, int out_size, void* d_ws,
                              size_t ws_size, hipStream_t stream) {
  (void)in_sizes; (void)n_in; (void)out_size; (void)ws_size;
  const float* X = (const float*)d_in[0];   // (64, 65536)
  const float* D = (const float*)d_in[1];   // (64, 512)
  float* out = (float*)d_out;               // (512, 65536)
  float* gram = (float*)d_ws;               // 1 MB scratch

  ksvd_prep<<<(NATOMS * NATOMS) / 256, 256, 0, stream>>>(D, gram);
  hipMemsetAsync(out, 0, (size_t)NATOMS * BATCH * sizeof(float), stream);
  ksvd_main<<<BATCH / BT, 256, 0, stream>>>(X, D, gram, out);
}